// Round 1
// baseline (172.369 us; speedup 1.0000x reference)
//
#include <hip/hip_runtime.h>

#define D_FEAT 32

__global__ void spmv_scatter_kernel(const int* __restrict__ edge_index,
                                    const float* __restrict__ edge_attr,
                                    const float* __restrict__ x,
                                    float* __restrict__ out,
                                    int n_edges) {
    const long long total = (long long)n_edges * D_FEAT;
    const long long stride = (long long)gridDim.x * blockDim.x;
    for (long long i = (long long)blockIdx.x * blockDim.x + threadIdx.x;
         i < total; i += stride) {
        const int e = (int)(i >> 5);          // edge id
        const int d = (int)(i & (D_FEAT - 1)); // feature id
        const int s  = edge_index[e];           // src (row 0)
        const int dd = edge_index[n_edges + e]; // dst (row 1)
        const float a = edge_attr[e];
        atomicAdd(&out[(long long)s * D_FEAT + d], a * x[(long long)dd * D_FEAT + d]);
    }
}

extern "C" void kernel_launch(void* const* d_in, const int* in_sizes, int n_in,
                              void* d_out, int out_size, void* d_ws, size_t ws_size,
                              hipStream_t stream) {
    const int* edge_index = (const int*)d_in[0];   // [2, E] int32
    const float* edge_attr = (const float*)d_in[1]; // [E] f32
    const float* x = (const float*)d_in[2];         // [N, 32] f32
    float* out = (float*)d_out;                     // [N, 32] f32

    const int n_edges = in_sizes[1];                // E from edge_attr

    // Zero output (harness poisons with 0xAA; we must re-zero every call).
    hipMemsetAsync(d_out, 0, (size_t)out_size * sizeof(float), stream);

    const int block = 256;
    long long total_threads = (long long)n_edges * D_FEAT;
    int grid = (int)((total_threads + block - 1) / block);
    if (grid > 65536) grid = 65536;

    spmv_scatter_kernel<<<grid, block, 0, stream>>>(edge_index, edge_attr, x, out, n_edges);
}